// Round 11
// baseline (293.107 us; speedup 1.0000x reference)
//
#include <hip/hip_runtime.h>
#include <hip/hip_bf16.h>

typedef __bf16 bf16;
typedef __attribute__((ext_vector_type(8))) __bf16 bf16x8;
typedef __attribute__((ext_vector_type(4))) __bf16 bf16x4;
typedef __attribute__((ext_vector_type(4))) float floatx4;

#define DM 1024
#define NH 16
#define HD 64
#define SEQ 2048
#define BATCH 4
#define MTOT (BATCH * SEQ) /* 8192 */

#define GLDS(g, l) \
  __builtin_amdgcn_global_load_lds((const __attribute__((address_space(1))) void*)(g), \
                                   (__attribute__((address_space(3))) void*)(l), 16, 0, 0)

// ---------------- fp32 -> bf16 convert (x) ----------------
__global__ void cvt_f32_bf16(const float* __restrict__ in, bf16* __restrict__ out, int n4) {
  int i = blockIdx.x * 256 + threadIdx.x;
  if (i < n4) {
    float4 v = ((const float4*)in)[i];
    bf16x4 o;
    o[0] = (bf16)v.x; o[1] = (bf16)v.y; o[2] = (bf16)v.z; o[3] = (bf16)v.w;
    ((bf16x4*)out)[i] = o;
  }
}

// ------------- fp32 [K][N] -> bf16 [N][K] transpose-convert, 4 mats in one launch -------------
__global__ void transpose_cvt4(const float* __restrict__ Wq, const float* __restrict__ Wk,
                               const float* __restrict__ Wv, const float* __restrict__ Wo,
                               bf16* __restrict__ Wqkvt, bf16* __restrict__ Wot) {
  __shared__ float tile[32][33];
  const float* W;
  bf16* Wt;
  int z = blockIdx.z;
  if (z == 0) { W = Wq; Wt = Wqkvt; }
  else if (z == 1) { W = Wk; Wt = Wqkvt + (size_t)DM * DM; }
  else if (z == 2) { W = Wv; Wt = Wqkvt + (size_t)2 * DM * DM; }
  else { W = Wo; Wt = Wot; }
  int n0 = blockIdx.x * 32, k0 = blockIdx.y * 32;
  int tx = threadIdx.x, ty = threadIdx.y; // 32 x 8
#pragma unroll
  for (int j = 0; j < 32; j += 8)
    tile[ty + j][tx] = W[(size_t)(k0 + ty + j) * DM + n0 + tx];
  __syncthreads();
#pragma unroll
  for (int j = 0; j < 32; j += 8)
    Wt[(size_t)(n0 + ty + j) * DM + k0 + tx] = (bf16)tile[tx][ty + j];
}

// ---------------- QKV projection GEMM: 128x128 tile, BK=64, XOR-swizzled LDS ----------------
#define BK 64

__global__ __launch_bounds__(256, 3) void gemm_qkv(const bf16* __restrict__ A,
                                                   const bf16* __restrict__ Bt,
                                                   bf16* __restrict__ Qb,
                                                   bf16* __restrict__ Kb,
                                                   bf16* __restrict__ Vt) {
  __shared__ __align__(16) bf16 Alds[128 * BK]; // 16 KB
  __shared__ __align__(16) bf16 Blds[128 * BK]; // 16 KB
  const int K = 1024;
  int m0 = blockIdx.x * 128;
  int n0 = blockIdx.y * 128;
  int tid = threadIdx.x;
  int wave = tid >> 6, lane = tid & 63;
  int wm = (wave & 1) * 64, wn = (wave >> 1) * 64;
  int lm = lane & 15, quad = lane >> 4;
  int lm7 = lm & 7;

  int cbase = wave * 64 + lane;
  const bf16* gA[4];
  const bf16* gB[4];
  bf16 *lA[4], *lB[4];
#pragma unroll
  for (int seg = 0; seg < 4; ++seg) {
    int c = seg * 256 + cbase;
    int row = c >> 3;
    int col8 = (c & 7) ^ (row & 7);
    gA[seg] = A + (size_t)(m0 + row) * K + col8 * 8;
    gB[seg] = Bt + (size_t)(n0 + row) * K + col8 * 8;
    lA[seg] = Alds + c * 8;
    lB[seg] = Blds + c * 8;
  }

  floatx4 acc[4][4] = {};
  for (int kt = 0; kt < K; kt += BK) {
    __syncthreads(); // prior tile frag reads done
#pragma unroll
    for (int seg = 0; seg < 4; ++seg) {
      GLDS(gA[seg] + kt, lA[seg]);
      GLDS(gB[seg] + kt, lB[seg]);
    }
    __syncthreads(); // vmcnt drained -> tile visible
#pragma unroll
    for (int ks = 0; ks < 2; ++ks) {
      int xk = (ks * 4 + quad) ^ lm7; // swizzled chunk column, loop-invariant
      bf16x8 af[4], bfr[4];
#pragma unroll
      for (int t = 0; t < 4; ++t) {
        af[t] = *(const bf16x8*)(Alds + (wm + t * 16 + lm) * BK + xk * 8);
        bfr[t] = *(const bf16x8*)(Blds + (wn + t * 16 + lm) * BK + xk * 8);
      }
#pragma unroll
      for (int i = 0; i < 4; ++i)
#pragma unroll
        for (int j = 0; j < 4; ++j)
          acc[i][j] = __builtin_amdgcn_mfma_f32_16x16x32_bf16(af[i], bfr[j], acc[i][j], 0, 0, 0);
    }
  }
#pragma unroll
  for (int i = 0; i < 4; ++i) {
#pragma unroll
    for (int j = 0; j < 4; ++j) {
#pragma unroll
      for (int r = 0; r < 4; ++r) {
        int R = m0 + wm + i * 16 + quad * 4 + r; // 0..8191
        int C = n0 + wn + j * 16 + lm;           // 0..3071
        int b = R >> 11, n = R & 2047;
        int proj = C >> 10, c = C & 1023;
        int h = c >> 6, d = c & 63;
        int bh = b * NH + h;
        bf16 bv = (bf16)acc[i][j][r];
        if (proj == 0)
          Qb[((size_t)bh * SEQ + n) * HD + d] = bv;
        else if (proj == 1)
          Kb[((size_t)bh * SEQ + n) * HD + d] = bv;
        else
          Vt[((size_t)bh * HD + d) * SEQ + n] = bv;
      }
    }
  }
}

// ---------------- output projection GEMM (+bias, fp32 out): 128x128, BK=64, swizzled ----------------
__global__ __launch_bounds__(256, 3) void gemm_out(const bf16* __restrict__ A,
                                                   const bf16* __restrict__ Bt,
                                                   const float* __restrict__ bias,
                                                   float* __restrict__ out) {
  __shared__ __align__(16) bf16 Alds[128 * BK];
  __shared__ __align__(16) bf16 Blds[128 * BK];
  const int K = 1024;
  int m0 = blockIdx.x * 128;
  int n0 = blockIdx.y * 128;
  int tid = threadIdx.x;
  int wave = tid >> 6, lane = tid & 63;
  int wm = (wave & 1) * 64, wn = (wave >> 1) * 64;
  int lm = lane & 15, quad = lane >> 4;
  int lm7 = lm & 7;

  int cbase = wave * 64 + lane;
  const bf16* gA[4];
  const bf16* gB[4];
  bf16 *lA[4], *lB[4];
#pragma unroll
  for (int seg = 0; seg < 4; ++seg) {
    int c = seg * 256 + cbase;
    int row = c >> 3;
    int col8 = (c & 7) ^ (row & 7);
    gA[seg] = A + (size_t)(m0 + row) * K + col8 * 8;
    gB[seg] = Bt + (size_t)(n0 + row) * K + col8 * 8;
    lA[seg] = Alds + c * 8;
    lB[seg] = Blds + c * 8;
  }

  floatx4 acc[4][4] = {};
  for (int kt = 0; kt < K; kt += BK) {
    __syncthreads();
#pragma unroll
    for (int seg = 0; seg < 4; ++seg) {
      GLDS(gA[seg] + kt, lA[seg]);
      GLDS(gB[seg] + kt, lB[seg]);
    }
    __syncthreads();
#pragma unroll
    for (int ks = 0; ks < 2; ++ks) {
      int xk = (ks * 4 + quad) ^ lm7;
      bf16x8 af[4], bfr[4];
#pragma unroll
      for (int t = 0; t < 4; ++t) {
        af[t] = *(const bf16x8*)(Alds + (wm + t * 16 + lm) * BK + xk * 8);
        bfr[t] = *(const bf16x8*)(Blds + (wn + t * 16 + lm) * BK + xk * 8);
      }
#pragma unroll
      for (int i = 0; i < 4; ++i)
#pragma unroll
        for (int j = 0; j < 4; ++j)
          acc[i][j] = __builtin_amdgcn_mfma_f32_16x16x32_bf16(af[i], bfr[j], acc[i][j], 0, 0, 0);
    }
  }
#pragma unroll
  for (int i = 0; i < 4; ++i)
#pragma unroll
    for (int j = 0; j < 4; ++j)
#pragma unroll
      for (int r = 0; r < 4; ++r) {
        int R = m0 + wm + i * 16 + quad * 4 + r;
        int C = n0 + wn + j * 16 + lm;
        out[(size_t)R * DM + C] = acc[i][j][r] + bias[C];
      }
}

// ---------------- flash attention v6: BQ=128/block, 32 q/wave, shared K/V frag reads ----
// S^T = MFMA(A=K, B=Q) per q-chunk; P register-resident; lsum via ones-row MFMA.
// exp folded: Q pre-scaled by 0.125*log2(e), P = exp2(st).
#define SKV 72 /* LDS row stride: 144 B, 16B-aligned */

__global__ __launch_bounds__(256) void attn(const bf16* __restrict__ Qb,
                                            const bf16* __restrict__ Kb,
                                            const bf16* __restrict__ Vt,
                                            bf16* __restrict__ ctx) {
  __shared__ __align__(16) bf16 Klds[64 * SKV]; // 9 KB
  __shared__ __align__(16) bf16 Vlds[64 * SKV]; // 9 KB
  int blk = blockIdx.x; // 512 blocks
  int xcd = blk & 7;
  int k = blk >> 3;     // 0..63
  int p = k & 7;        // pair index 0..7 (128-row q-tiles)
  int bh = (k >> 3) * 8 + xcd; // 8 pair-blocks of bh share (blk mod 8) -> same XCD
  int tid = threadIdx.x, wave = tid >> 6, lane = tid & 63;
  int lm = lane & 15, quad = lane >> 4;
  const bf16* Qp = Qb + (size_t)bh * SEQ * HD;
  const bf16* Kp = Kb + (size_t)bh * SEQ * HD;
  const bf16* Vp = Vt + (size_t)bh * HD * SEQ;
  int sr = tid >> 3, sc = (tid & 7) * 8; // staging: row 0..31, col-elem offset
  int b = bh >> 4, h = bh & 15;
  const float QSCALE = 0.125f * 1.4426950408889634f; // fold 1/sqrt(64) and log2(e)

  bf16x8 ones; // A-frag with row m=0 all-ones: lsum = MFMA(ones, P)
#pragma unroll
  for (int j = 0; j < 8; ++j) ones[j] = (lm == 0) ? (bf16)1.0f : (bf16)0.0f;

#pragma unroll 1
  for (int phase = 0; phase < 2; ++phase) {
    int qt = phase ? (15 - p) : p;
    int q0 = qt * 128;
    int rowbase = q0 + wave * 32; // this wave: q rows rowbase..rowbase+31 (chunks A,B)

    // Q B-fragments for chunks A (+lm) and B (+16+lm), pre-scaled
    bf16x8 qfA[2], qfB[2];
#pragma unroll
    for (int ks2 = 0; ks2 < 2; ++ks2) {
      bf16x8 qa = *(const bf16x8*)(Qp + (size_t)(rowbase + lm) * HD + ks2 * 32 + quad * 8);
      bf16x8 qb = *(const bf16x8*)(Qp + (size_t)(rowbase + 16 + lm) * HD + ks2 * 32 + quad * 8);
#pragma unroll
      for (int j = 0; j < 8; ++j) {
        qa[j] = (bf16)((float)qa[j] * QSCALE);
        qb[j] = (bf16)((float)qb[j] * QSCALE);
      }
      qfA[ks2] = qa;
      qfB[ks2] = qb;
    }

    floatx4 accA[4] = {}, accB[4] = {}; // O^T frags per chunk
    floatx4 aclA = {}, aclB = {};       // lsum accumulators (row 0 meaningful)
    int nkv = 2 * qt + 2;

    // prologue: tile 0 -> regs -> LDS (barrier first: prior phase readers done)
    bf16x8 ka0 = *(const bf16x8*)(Kp + (size_t)sr * HD + sc);
    bf16x8 ka1 = *(const bf16x8*)(Kp + (size_t)(32 + sr) * HD + sc);
    bf16x8 va0 = *(const bf16x8*)(Vp + (size_t)sr * SEQ + sc);
    bf16x8 va1 = *(const bf16x8*)(Vp + (size_t)(32 + sr) * SEQ + sc);
    __syncthreads();
    *(bf16x8*)(Klds + sr * SKV + sc) = ka0;
    *(bf16x8*)(Klds + (32 + sr) * SKV + sc) = ka1;
    *(bf16x8*)(Vlds + sr * SKV + sc) = va0;
    *(bf16x8*)(Vlds + (32 + sr) * SKV + sc) = va1;

#pragma unroll 1
    for (int t = 0; t < nkv; ++t) {
      __syncthreads(); // staged tile visible
      int kv0 = t * 64;
      if (t + 1 < nkv) { // prefetch next tile into regs (overlaps compute)
        int kn = kv0 + 64;
        ka0 = *(const bf16x8*)(Kp + (size_t)(kn + sr) * HD + sc);
        ka1 = *(const bf16x8*)(Kp + (size_t)(kn + 32 + sr) * HD + sc);
        va0 = *(const bf16x8*)(Vp + (size_t)sr * SEQ + kn + sc);
        va1 = *(const bf16x8*)(Vp + (size_t)(32 + sr) * SEQ + kn + sc);
      }

      if (kv0 <= rowbase + 31) { // wave-uniform: tile not fully masked for this wave
        // S^T = K Q^T, both q-chunks share kf reads
        floatx4 stA[4] = {}, stB[4] = {};
#pragma unroll
        for (int mt = 0; mt < 4; ++mt) {
          bf16x8 kf0 = *(const bf16x8*)(Klds + (mt * 16 + lm) * SKV + quad * 8);
          bf16x8 kf1 = *(const bf16x8*)(Klds + (mt * 16 + lm) * SKV + 32 + quad * 8);
          stA[mt] = __builtin_amdgcn_mfma_f32_16x16x32_bf16(kf0, qfA[0], stA[mt], 0, 0, 0);
          stA[mt] = __builtin_amdgcn_mfma_f32_16x16x32_bf16(kf1, qfA[1], stA[mt], 0, 0, 0);
          stB[mt] = __builtin_amdgcn_mfma_f32_16x16x32_bf16(kf0, qfB[0], stB[mt], 0, 0, 0);
          stB[mt] = __builtin_amdgcn_mfma_f32_16x16x32_bf16(kf1, qfB[1], stB[mt], 0, 0, 0);
        }

        // P = exp2(st), register-resident
        bf16x4 pbA[4], pbB[4];
        if (kv0 + 63 <= rowbase) { // fully unmasked for both chunks
#pragma unroll
          for (int mt = 0; mt < 4; ++mt)
#pragma unroll
            for (int r = 0; r < 4; ++r) {
              pbA[mt][r] = (bf16)exp2f(stA[mt][r]);
              pbB[mt][r] = (bf16)exp2f(stB[mt][r]);
            }
        } else { // diagonal region: causal mask per lane
          int qrelA = rowbase - kv0 + lm;
          int qrelB = qrelA + 16;
#pragma unroll
          for (int mt = 0; mt < 4; ++mt)
#pragma unroll
            for (int r = 0; r < 4; ++r) {
              int kvrel = mt * 16 + quad * 4 + r;
              float pa = exp2f(stA[mt][r]);
              float pbv = exp2f(stB[mt][r]);
              if (kvrel > qrelA) pa = 0.f;
              if (kvrel > qrelB) pbv = 0.f;
              pbA[mt][r] = (bf16)pa;
              pbB[mt][r] = (bf16)pbv;
            }
        }

        // O^T += V P ; lsum via ones-row MFMA; vf reads shared across chunks
#pragma unroll
        for (int ks = 0; ks < 2; ++ks) {
          bf16x8 pfA, pfB;
#pragma unroll
          for (int j = 0; j < 4; ++j) {
            pfA[j] = pbA[2 * ks][j]; pfA[4 + j] = pbA[2 * ks + 1][j];
            pfB[j] = pbB[2 * ks][j]; pfB[4 + j] = pbB[2 * ks + 1][j];
          }
          aclA = __builtin_amdgcn_mfma_f32_16x16x32_bf16(ones, pfA, aclA, 0, 0, 0);
          aclB = __builtin_amdgcn_mfma_f32_16x16x32_bf16(ones, pfB, aclB, 0, 0, 0);
#pragma unroll
          for (int db = 0; db < 4; ++db) {
            const bf16* vrow = Vlds + (db * 16 + lm) * SKV + ks * 32 + quad * 4;
            bf16x4 v0 = *(const bf16x4*)(vrow);      // kv = ks*32 + quad*4 + (0..3)
            bf16x4 v1 = *(const bf16x4*)(vrow + 16); // kv = ks*32 + 16 + quad*4 + (0..3)
            bf16x8 vf;
#pragma unroll
            for (int j = 0; j < 4; ++j) { vf[j] = v0[j]; vf[4 + j] = v1[j]; }
            accA[db] = __builtin_amdgcn_mfma_f32_16x16x32_bf16(vf, pfA, accA[db], 0, 0, 0);
            accB[db] = __builtin_amdgcn_mfma_f32_16x16x32_bf16(vf, pfB, accB[db], 0, 0, 0);
          }
        }
      }

      if (t + 1 < nkv) {
        __syncthreads(); // all waves done reading tile t
        *(bf16x8*)(Klds + sr * SKV + sc) = ka0;
        *(bf16x8*)(Klds + (32 + sr) * SKV + sc) = ka1;
        *(bf16x8*)(Vlds + sr * SKV + sc) = va0;
        *(bf16x8*)(Vlds + (32 + sr) * SKV + sc) = va1;
      }
    }

    // lsum lives in lanes (quad=0, lm), reg 0 of acl — broadcast to all lanes
    float linvA = 1.0f / __shfl(aclA[0], lm, 64);
    float linvB = 1.0f / __shfl(aclB[0], lm, 64);

    // epilogue: lane holds O^T[d=db*16+quad*4+r][q]; pack 4 consecutive d -> 8B store
    bf16* crowA = ctx + ((size_t)b * SEQ + rowbase + lm) * DM + h * 64;
    bf16* crowB = crowA + (size_t)16 * DM;
#pragma unroll
    for (int db = 0; db < 4; ++db) {
      bf16x4 oa, ob;
#pragma unroll
      for (int r = 0; r < 4; ++r) {
        oa[r] = (bf16)(accA[db][r] * linvA);
        ob[r] = (bf16)(accB[db][r] * linvB);
      }
      *(bf16x4*)(crowA + db * 16 + quad * 4) = oa;
      *(bf16x4*)(crowB + db * 16 + quad * 4) = ob;
    }
  }
}

extern "C" void kernel_launch(void* const* d_in, const int* in_sizes, int n_in,
                              void* d_out, int out_size, void* d_ws, size_t ws_size,
                              hipStream_t stream) {
  const float* x = (const float*)d_in[0];
  const float* Wq = (const float*)d_in[1];
  const float* Wk = (const float*)d_in[2];
  const float* Wv = (const float*)d_in[3];
  const float* Wo = (const float*)d_in[4];
  const float* bo = (const float*)d_in[5];
  float* out = (float*)d_out;

  bf16* ws = (bf16*)d_ws;
  bf16* xb = ws;                                   // 8M elems, reused as ctx
  bf16* Wqkvt = xb + (size_t)MTOT * DM;            // 3M elems
  bf16* Wot = Wqkvt + (size_t)3 * DM * DM;         // 1M elems
  bf16* Qb = Wot + (size_t)DM * DM;                // 8M elems
  bf16* Kb = Qb + (size_t)BATCH * NH * SEQ * HD;   // 8M elems
  bf16* Vtb = Kb + (size_t)BATCH * NH * SEQ * HD;  // 8M elems
  bf16* ctx = xb;                                  // reuse after QKV GEMM

  cvt_f32_bf16<<<(MTOT * DM / 4 + 255) / 256, 256, 0, stream>>>(x, xb, MTOT * DM / 4);
  transpose_cvt4<<<dim3(32, 32, 4), dim3(32, 8), 0, stream>>>(Wq, Wk, Wv, Wo, Wqkvt, Wot);
  gemm_qkv<<<dim3(MTOT / 128, 3 * DM / 128), 256, 0, stream>>>(xb, Wqkvt, Qb, Kb, Vtb);
  attn<<<512, 256, 0, stream>>>(Qb, Kb, Vtb, ctx);
  gemm_out<<<dim3(MTOT / 128, DM / 128), 256, 0, stream>>>(ctx, Wot, bo, out);
}

// Round 12
// 247.861 us; speedup vs baseline: 1.1825x; 1.1825x over previous
//
#include <hip/hip_runtime.h>
#include <hip/hip_bf16.h>

typedef __bf16 bf16;
typedef __attribute__((ext_vector_type(8))) __bf16 bf16x8;
typedef __attribute__((ext_vector_type(4))) __bf16 bf16x4;
typedef __attribute__((ext_vector_type(4))) float floatx4;

#define DM 1024
#define NH 16
#define HD 64
#define SEQ 2048
#define BATCH 4
#define MTOT (BATCH * SEQ) /* 8192 */

#define GLDS(g, l) \
  __builtin_amdgcn_global_load_lds((const __attribute__((address_space(1))) void*)(g), \
                                   (__attribute__((address_space(3))) void*)(l), 16, 0, 0)

// ---------------- fp32 -> bf16 convert (x) ----------------
__global__ void cvt_f32_bf16(const float* __restrict__ in, bf16* __restrict__ out, int n4) {
  int i = blockIdx.x * 256 + threadIdx.x;
  if (i < n4) {
    float4 v = ((const float4*)in)[i];
    bf16x4 o;
    o[0] = (bf16)v.x; o[1] = (bf16)v.y; o[2] = (bf16)v.z; o[3] = (bf16)v.w;
    ((bf16x4*)out)[i] = o;
  }
}

// ------------- fp32 [K][N] -> bf16 [N][K] transpose-convert, 4 mats in one launch -------------
__global__ void transpose_cvt4(const float* __restrict__ Wq, const float* __restrict__ Wk,
                               const float* __restrict__ Wv, const float* __restrict__ Wo,
                               bf16* __restrict__ Wqkvt, bf16* __restrict__ Wot) {
  __shared__ float tile[32][33];
  const float* W;
  bf16* Wt;
  int z = blockIdx.z;
  if (z == 0) { W = Wq; Wt = Wqkvt; }
  else if (z == 1) { W = Wk; Wt = Wqkvt + (size_t)DM * DM; }
  else if (z == 2) { W = Wv; Wt = Wqkvt + (size_t)2 * DM * DM; }
  else { W = Wo; Wt = Wot; }
  int n0 = blockIdx.x * 32, k0 = blockIdx.y * 32;
  int tx = threadIdx.x, ty = threadIdx.y; // 32 x 8
#pragma unroll
  for (int j = 0; j < 32; j += 8)
    tile[ty + j][tx] = W[(size_t)(k0 + ty + j) * DM + n0 + tx];
  __syncthreads();
#pragma unroll
  for (int j = 0; j < 32; j += 8)
    Wt[(size_t)(n0 + ty + j) * DM + k0 + tx] = (bf16)tile[tx][ty + j];
}

// ---------------- QKV projection GEMM: 128x128 tile, BK=64, XOR-swizzled LDS ----------------
#define BK 64

__global__ __launch_bounds__(256, 3) void gemm_qkv(const bf16* __restrict__ A,
                                                   const bf16* __restrict__ Bt,
                                                   bf16* __restrict__ Qb,
                                                   bf16* __restrict__ Kb,
                                                   bf16* __restrict__ Vt) {
  __shared__ __align__(16) bf16 Alds[128 * BK]; // 16 KB
  __shared__ __align__(16) bf16 Blds[128 * BK]; // 16 KB
  const int K = 1024;
  int m0 = blockIdx.x * 128;
  int n0 = blockIdx.y * 128;
  int tid = threadIdx.x;
  int wave = tid >> 6, lane = tid & 63;
  int wm = (wave & 1) * 64, wn = (wave >> 1) * 64;
  int lm = lane & 15, quad = lane >> 4;
  int lm7 = lm & 7;

  int cbase = wave * 64 + lane;
  const bf16* gA[4];
  const bf16* gB[4];
  bf16 *lA[4], *lB[4];
#pragma unroll
  for (int seg = 0; seg < 4; ++seg) {
    int c = seg * 256 + cbase;
    int row = c >> 3;
    int col8 = (c & 7) ^ (row & 7);
    gA[seg] = A + (size_t)(m0 + row) * K + col8 * 8;
    gB[seg] = Bt + (size_t)(n0 + row) * K + col8 * 8;
    lA[seg] = Alds + c * 8;
    lB[seg] = Blds + c * 8;
  }

  floatx4 acc[4][4] = {};
  for (int kt = 0; kt < K; kt += BK) {
    __syncthreads(); // prior tile frag reads done
#pragma unroll
    for (int seg = 0; seg < 4; ++seg) {
      GLDS(gA[seg] + kt, lA[seg]);
      GLDS(gB[seg] + kt, lB[seg]);
    }
    __syncthreads(); // vmcnt drained -> tile visible
#pragma unroll
    for (int ks = 0; ks < 2; ++ks) {
      int xk = (ks * 4 + quad) ^ lm7; // swizzled chunk column, loop-invariant
      bf16x8 af[4], bfr[4];
#pragma unroll
      for (int t = 0; t < 4; ++t) {
        af[t] = *(const bf16x8*)(Alds + (wm + t * 16 + lm) * BK + xk * 8);
        bfr[t] = *(const bf16x8*)(Blds + (wn + t * 16 + lm) * BK + xk * 8);
      }
#pragma unroll
      for (int i = 0; i < 4; ++i)
#pragma unroll
        for (int j = 0; j < 4; ++j)
          acc[i][j] = __builtin_amdgcn_mfma_f32_16x16x32_bf16(af[i], bfr[j], acc[i][j], 0, 0, 0);
    }
  }
#pragma unroll
  for (int i = 0; i < 4; ++i) {
#pragma unroll
    for (int j = 0; j < 4; ++j) {
#pragma unroll
      for (int r = 0; r < 4; ++r) {
        int R = m0 + wm + i * 16 + quad * 4 + r; // 0..8191
        int C = n0 + wn + j * 16 + lm;           // 0..3071
        int b = R >> 11, n = R & 2047;
        int proj = C >> 10, c = C & 1023;
        int h = c >> 6, d = c & 63;
        int bh = b * NH + h;
        bf16 bv = (bf16)acc[i][j][r];
        if (proj == 0)
          Qb[((size_t)bh * SEQ + n) * HD + d] = bv;
        else if (proj == 1)
          Kb[((size_t)bh * SEQ + n) * HD + d] = bv;
        else
          Vt[((size_t)bh * HD + d) * SEQ + n] = bv;
      }
    }
  }
}

// ---------------- output projection GEMM (+bias, fp32 out): 128x128, BK=64, swizzled ----------------
__global__ __launch_bounds__(256, 3) void gemm_out(const bf16* __restrict__ A,
                                                   const bf16* __restrict__ Bt,
                                                   const float* __restrict__ bias,
                                                   float* __restrict__ out) {
  __shared__ __align__(16) bf16 Alds[128 * BK];
  __shared__ __align__(16) bf16 Blds[128 * BK];
  const int K = 1024;
  int m0 = blockIdx.x * 128;
  int n0 = blockIdx.y * 128;
  int tid = threadIdx.x;
  int wave = tid >> 6, lane = tid & 63;
  int wm = (wave & 1) * 64, wn = (wave >> 1) * 64;
  int lm = lane & 15, quad = lane >> 4;
  int lm7 = lm & 7;

  int cbase = wave * 64 + lane;
  const bf16* gA[4];
  const bf16* gB[4];
  bf16 *lA[4], *lB[4];
#pragma unroll
  for (int seg = 0; seg < 4; ++seg) {
    int c = seg * 256 + cbase;
    int row = c >> 3;
    int col8 = (c & 7) ^ (row & 7);
    gA[seg] = A + (size_t)(m0 + row) * K + col8 * 8;
    gB[seg] = Bt + (size_t)(n0 + row) * K + col8 * 8;
    lA[seg] = Alds + c * 8;
    lB[seg] = Blds + c * 8;
  }

  floatx4 acc[4][4] = {};
  for (int kt = 0; kt < K; kt += BK) {
    __syncthreads();
#pragma unroll
    for (int seg = 0; seg < 4; ++seg) {
      GLDS(gA[seg] + kt, lA[seg]);
      GLDS(gB[seg] + kt, lB[seg]);
    }
    __syncthreads();
#pragma unroll
    for (int ks = 0; ks < 2; ++ks) {
      int xk = (ks * 4 + quad) ^ lm7;
      bf16x8 af[4], bfr[4];
#pragma unroll
      for (int t = 0; t < 4; ++t) {
        af[t] = *(const bf16x8*)(Alds + (wm + t * 16 + lm) * BK + xk * 8);
        bfr[t] = *(const bf16x8*)(Blds + (wn + t * 16 + lm) * BK + xk * 8);
      }
#pragma unroll
      for (int i = 0; i < 4; ++i)
#pragma unroll
        for (int j = 0; j < 4; ++j)
          acc[i][j] = __builtin_amdgcn_mfma_f32_16x16x32_bf16(af[i], bfr[j], acc[i][j], 0, 0, 0);
    }
  }
#pragma unroll
  for (int i = 0; i < 4; ++i)
#pragma unroll
    for (int j = 0; j < 4; ++j)
#pragma unroll
      for (int r = 0; r < 4; ++r) {
        int R = m0 + wm + i * 16 + quad * 4 + r;
        int C = n0 + wn + j * 16 + lm;
        out[(size_t)R * DM + C] = acc[i][j][r] + bias[C];
      }
}

// ---------------- flash attention v7: BQ=128, 32 q/wave, NO pairing, LPT order ----
// Grid 1024: blk -> xcd=blk&7, idx=blk>>3; bh=(idx&7)*8+xcd (same XCD per bh),
// qt = 15-(idx>>3) (big blocks dispatch first -> LPT smoothing).
// S^T = MFMA(A=K, B=Q) per q-chunk; P register-resident; lsum via ones-row MFMA.
#define SKV 72 /* LDS row stride: 144 B, 16B-aligned */

__global__ __launch_bounds__(256) void attn(const bf16* __restrict__ Qb,
                                            const bf16* __restrict__ Kb,
                                            const bf16* __restrict__ Vt,
                                            bf16* __restrict__ ctx) {
  __shared__ __align__(16) bf16 Klds[64 * SKV]; // 9 KB
  __shared__ __align__(16) bf16 Vlds[64 * SKV]; // 9 KB
  int blk = blockIdx.x; // 1024 blocks
  int xcd = blk & 7;
  int idx = blk >> 3;          // 0..127
  int bh = (idx & 7) * 8 + xcd;
  int qt = 15 - (idx >> 3);    // descending -> LPT
  int tid = threadIdx.x, wave = tid >> 6, lane = tid & 63;
  int lm = lane & 15, quad = lane >> 4;
  const bf16* Qp = Qb + (size_t)bh * SEQ * HD;
  const bf16* Kp = Kb + (size_t)bh * SEQ * HD;
  const bf16* Vp = Vt + (size_t)bh * HD * SEQ;
  int sr = tid >> 3, sc = (tid & 7) * 8; // staging: row 0..31, col-elem offset
  int b = bh >> 4, h = bh & 15;
  const float QSCALE = 0.125f * 1.4426950408889634f; // fold 1/sqrt(64) and log2(e)

  bf16x8 ones; // A-frag with row m=0 all-ones: lsum = MFMA(ones, P)
#pragma unroll
  for (int j = 0; j < 8; ++j) ones[j] = (lm == 0) ? (bf16)1.0f : (bf16)0.0f;

  int q0 = qt * 128;
  int rowbase = q0 + wave * 32; // this wave: q rows rowbase..rowbase+31 (chunks A,B)

  // Q B-fragments for chunks A (+lm) and B (+16+lm), pre-scaled
  bf16x8 qfA[2], qfB[2];
#pragma unroll
  for (int ks2 = 0; ks2 < 2; ++ks2) {
    bf16x8 qa = *(const bf16x8*)(Qp + (size_t)(rowbase + lm) * HD + ks2 * 32 + quad * 8);
    bf16x8 qb = *(const bf16x8*)(Qp + (size_t)(rowbase + 16 + lm) * HD + ks2 * 32 + quad * 8);
#pragma unroll
    for (int j = 0; j < 8; ++j) {
      qa[j] = (bf16)((float)qa[j] * QSCALE);
      qb[j] = (bf16)((float)qb[j] * QSCALE);
    }
    qfA[ks2] = qa;
    qfB[ks2] = qb;
  }

  floatx4 accA[4] = {}, accB[4] = {}; // O^T frags per chunk
  floatx4 aclA = {}, aclB = {};       // lsum accumulators (row 0 meaningful)
  int nkv = 2 * qt + 2;

  // prologue: tile 0 -> regs -> LDS
  bf16x8 ka0 = *(const bf16x8*)(Kp + (size_t)sr * HD + sc);
  bf16x8 ka1 = *(const bf16x8*)(Kp + (size_t)(32 + sr) * HD + sc);
  bf16x8 va0 = *(const bf16x8*)(Vp + (size_t)sr * SEQ + sc);
  bf16x8 va1 = *(const bf16x8*)(Vp + (size_t)(32 + sr) * SEQ + sc);
  *(bf16x8*)(Klds + sr * SKV + sc) = ka0;
  *(bf16x8*)(Klds + (32 + sr) * SKV + sc) = ka1;
  *(bf16x8*)(Vlds + sr * SKV + sc) = va0;
  *(bf16x8*)(Vlds + (32 + sr) * SKV + sc) = va1;

#pragma unroll 1
  for (int t = 0; t < nkv; ++t) {
    __syncthreads(); // staged tile visible
    int kv0 = t * 64;
    if (t + 1 < nkv) { // prefetch next tile into regs (overlaps compute)
      int kn = kv0 + 64;
      ka0 = *(const bf16x8*)(Kp + (size_t)(kn + sr) * HD + sc);
      ka1 = *(const bf16x8*)(Kp + (size_t)(kn + 32 + sr) * HD + sc);
      va0 = *(const bf16x8*)(Vp + (size_t)sr * SEQ + kn + sc);
      va1 = *(const bf16x8*)(Vp + (size_t)(32 + sr) * SEQ + kn + sc);
    }

    if (kv0 <= rowbase + 31) { // wave-uniform: tile not fully masked for this wave
      // S^T = K Q^T, both q-chunks share kf reads
      floatx4 stA[4] = {}, stB[4] = {};
#pragma unroll
      for (int mt = 0; mt < 4; ++mt) {
        bf16x8 kf0 = *(const bf16x8*)(Klds + (mt * 16 + lm) * SKV + quad * 8);
        bf16x8 kf1 = *(const bf16x8*)(Klds + (mt * 16 + lm) * SKV + 32 + quad * 8);
        stA[mt] = __builtin_amdgcn_mfma_f32_16x16x32_bf16(kf0, qfA[0], stA[mt], 0, 0, 0);
        stA[mt] = __builtin_amdgcn_mfma_f32_16x16x32_bf16(kf1, qfA[1], stA[mt], 0, 0, 0);
        stB[mt] = __builtin_amdgcn_mfma_f32_16x16x32_bf16(kf0, qfB[0], stB[mt], 0, 0, 0);
        stB[mt] = __builtin_amdgcn_mfma_f32_16x16x32_bf16(kf1, qfB[1], stB[mt], 0, 0, 0);
      }

      // P = exp2(st), register-resident
      bf16x4 pbA[4], pbB[4];
      if (kv0 + 63 <= rowbase) { // fully unmasked for both chunks
#pragma unroll
        for (int mt = 0; mt < 4; ++mt)
#pragma unroll
          for (int r = 0; r < 4; ++r) {
            pbA[mt][r] = (bf16)exp2f(stA[mt][r]);
            pbB[mt][r] = (bf16)exp2f(stB[mt][r]);
          }
      } else { // diagonal region: causal mask per lane
        int qrelA = rowbase - kv0 + lm;
        int qrelB = qrelA + 16;
#pragma unroll
        for (int mt = 0; mt < 4; ++mt)
#pragma unroll
          for (int r = 0; r < 4; ++r) {
            int kvrel = mt * 16 + quad * 4 + r;
            float pa = exp2f(stA[mt][r]);
            float pbv = exp2f(stB[mt][r]);
            if (kvrel > qrelA) pa = 0.f;
            if (kvrel > qrelB) pbv = 0.f;
            pbA[mt][r] = (bf16)pa;
            pbB[mt][r] = (bf16)pbv;
          }
      }

      // O^T += V P ; lsum via ones-row MFMA; vf reads shared across chunks
#pragma unroll
      for (int ks = 0; ks < 2; ++ks) {
        bf16x8 pfA, pfB;
#pragma unroll
        for (int j = 0; j < 4; ++j) {
          pfA[j] = pbA[2 * ks][j]; pfA[4 + j] = pbA[2 * ks + 1][j];
          pfB[j] = pbB[2 * ks][j]; pfB[4 + j] = pbB[2 * ks + 1][j];
        }
        aclA = __builtin_amdgcn_mfma_f32_16x16x32_bf16(ones, pfA, aclA, 0, 0, 0);
        aclB = __builtin_amdgcn_mfma_f32_16x16x32_bf16(ones, pfB, aclB, 0, 0, 0);
#pragma unroll
        for (int db = 0; db < 4; ++db) {
          const bf16* vrow = Vlds + (db * 16 + lm) * SKV + ks * 32 + quad * 4;
          bf16x4 v0 = *(const bf16x4*)(vrow);      // kv = ks*32 + quad*4 + (0..3)
          bf16x4 v1 = *(const bf16x4*)(vrow + 16); // kv = ks*32 + 16 + quad*4 + (0..3)
          bf16x8 vf;
#pragma unroll
          for (int j = 0; j < 4; ++j) { vf[j] = v0[j]; vf[4 + j] = v1[j]; }
          accA[db] = __builtin_amdgcn_mfma_f32_16x16x32_bf16(vf, pfA, accA[db], 0, 0, 0);
          accB[db] = __builtin_amdgcn_mfma_f32_16x16x32_bf16(vf, pfB, accB[db], 0, 0, 0);
        }
      }
    }

    if (t + 1 < nkv) {
      __syncthreads(); // all waves done reading tile t
      *(bf16x8*)(Klds + sr * SKV + sc) = ka0;
      *(bf16x8*)(Klds + (32 + sr) * SKV + sc) = ka1;
      *(bf16x8*)(Vlds + sr * SKV + sc) = va0;
      *(bf16x8*)(Vlds + (32 + sr) * SKV + sc) = va1;
    }
  }

  // lsum lives in lanes (quad=0, lm), reg 0 of acl — broadcast to all lanes
  float linvA = 1.0f / __shfl(aclA[0], lm, 64);
  float linvB = 1.0f / __shfl(aclB[0], lm, 64);

  // epilogue: lane holds O^T[d=db*16+quad*4+r][q]; pack 4 consecutive d -> 8B store
  bf16* crowA = ctx + ((size_t)b * SEQ + rowbase + lm) * DM + h * 64;
  bf16* crowB = crowA + (size_t)16 * DM;
#pragma unroll
  for (int db = 0; db < 4; ++db) {
    bf16x4 oa, ob;
#pragma unroll
    for (int r = 0; r < 4; ++r) {
      oa[r] = (bf16)(accA[db][r] * linvA);
      ob[r] = (bf16)(accB[db][r] * linvB);
    }
    *(bf16x4*)(crowA + db * 16 + quad * 4) = oa;
    *(bf16x4*)(crowB + db * 16 + quad * 4) = ob;
  }
}

extern "C" void kernel_launch(void* const* d_in, const int* in_sizes, int n_in,
                              void* d_out, int out_size, void* d_ws, size_t ws_size,
                              hipStream_t stream) {
  const float* x = (const float*)d_in[0];
  const float* Wq = (const float*)d_in[1];
  const float* Wk = (const float*)d_in[2];
  const float* Wv = (const float*)d_in[3];
  const float* Wo = (const float*)d_in[4];
  const float* bo = (const float*)d_in[5];
  float* out = (float*)d_out;

  bf16* ws = (bf16*)d_ws;
  bf16* xb = ws;                                   // 8M elems, reused as ctx
  bf16* Wqkvt = xb + (size_t)MTOT * DM;            // 3M elems
  bf16* Wot = Wqkvt + (size_t)3 * DM * DM;         // 1M elems
  bf16* Qb = Wot + (size_t)DM * DM;                // 8M elems
  bf16* Kb = Qb + (size_t)BATCH * NH * SEQ * HD;   // 8M elems
  bf16* Vtb = Kb + (size_t)BATCH * NH * SEQ * HD;  // 8M elems
  bf16* ctx = xb;                                  // reuse after QKV GEMM

  cvt_f32_bf16<<<(MTOT * DM / 4 + 255) / 256, 256, 0, stream>>>(x, xb, MTOT * DM / 4);
  transpose_cvt4<<<dim3(32, 32, 4), dim3(32, 8), 0, stream>>>(Wq, Wk, Wv, Wo, Wqkvt, Wot);
  gemm_qkv<<<dim3(MTOT / 128, 3 * DM / 128), 256, 0, stream>>>(xb, Wqkvt, Qb, Kb, Vtb);
  attn<<<1024, 256, 0, stream>>>(Qb, Kb, Vtb, ctx);
  gemm_out<<<dim3(MTOT / 128, DM / 128), 256, 0, stream>>>(ctx, Wot, bo, out);
}